// Round 1
// baseline (202.751 us; speedup 1.0000x reference)
//
#include <hip/hip_runtime.h>

// B=32, T=2048, E=128, fp32. S (B,T,T) never materialized.
// R-this: Gram-matrix restructure:
//   M[b] = X2[b]^T X1[b]  (E x E), sx = column sums, xw[t] = x.W + bias
//   all in ONE pass over x (KA).  c1 = M.sx2/T, c2 = M^T.sx1/T  (KB, tiny).
//   et += c.U  t-chunked with c in LDS (KC: U traffic 64MB -> 2MB).
//   softmax (KD), o-pass (KE = proven K5).
// x1/x2 HBM passes: 3 -> 2. K2's shuffle chains and K3's per-CU 1MB U pull
// are both eliminated. Extra cost: 17MB M-partial write + 17MB read.

#define B_ 32
#define T_ 2048
#define E_ 128
#define EV (E_/4)
#define INV_T (1.0f/2048.0f)

// ws float offsets (every slot written before read -> no zeroing needed)
#define WS_PSX1 0                       // B*16*E = 65536
#define WS_PSX2 65536                   // B*16*E
#define WS_PM   131072                  // B*8*E*E = 4194304 (per-chunk Gram partials)
#define WS_ET1  4325376                 // B*T (xw base -> et -> probs)
#define WS_ET2  (WS_ET1 + 65536)        // B*T
#define WS_C1   (WS_ET2 + 65536)        // B*E
#define WS_C2   (WS_C1 + 4096)          // B*E

__device__ __forceinline__ float dot4(float4 a, float4 b) {
    return a.x*b.x + a.y*b.y + a.z*b.z + a.w*b.w;
}
__device__ __forceinline__ void fma4(float4& a, float s, const float4 v) {
    a.x += s*v.x; a.y += s*v.y; a.z += s*v.z; a.w += s*v.w;
}
__device__ __forceinline__ void add4(float4& a, const float4 v) {
    a.x += v.x; a.y += v.y; a.z += v.z; a.w += v.w;
}

// ---- KA: single pass over x: Gram partials M_g = X2c^T X1c, psx, xw bases ----
// grid (B, 8): 256 rows/block, 16-row double-buffered LDS chunks.
// 512 thr: thread (ty=tid>>5, tx=tid&31) owns M[ty*8..+8][tx*4..+4] (32 acc).
__global__ __launch_bounds__(512)
void ka_gram(const float* __restrict__ x1, const float* __restrict__ x2,
             const float* __restrict__ W1, const float* __restrict__ b1,
             const float* __restrict__ W2, const float* __restrict__ b2,
             float* __restrict__ ws) {
    __shared__ float4 sbuf[2][2][16][32];   // [dbuf][tensor][row][col4] = 32 KB
    __shared__ float4 sW[2][32];
    const int b = blockIdx.x, g = blockIdx.y, tid = threadIdx.x;
    if (tid < 64) sW[tid>>5][tid&31] = ((const float4*)((tid < 32) ? W1 : W2))[tid&31];
    const float4* x14 = (const float4*)x1 + ((size_t)b*T_ + g*256)*EV;
    const float4* x24 = (const float4*)x2 + ((size_t)b*T_ + g*256)*EV;
    const int ty = tid>>5, tx = tid&31;             // also staging (row,col4)
    const int p_ten = tid>>8, p_half = (tid>>7)&1, p_col = tid&127;
    const int xr = tid>>4, xl = tid&15;             // 32 dot-groups of 16 lanes
    const int xrow = xr>>1, xten = xr&1;

    float4 acc[8];
    #pragma unroll
    for (int i = 0; i < 8; ++i) acc[i] = make_float4(0.f,0.f,0.f,0.f);
    float psx_acc = 0.f;

    float* et_out = ws + (xten ? WS_ET2 : WS_ET1) + (size_t)b*T_;
    const float* bias = xten ? b2 : b1;

    // prologue: stage chunk 0
    sbuf[0][0][ty][tx] = x14[tid];
    sbuf[0][1][ty][tx] = x24[tid];
    __syncthreads();

    for (int k = 0; k < 16; ++k) {
        const int p = k & 1;
        float4 n0, n1;
        if (k < 15) { n0 = x14[(k+1)*512 + tid]; n1 = x24[(k+1)*512 + tid]; }

        // Gram rank-16 update: M[e,f] += x2[t,e]*x1[t,f]
        #pragma unroll
        for (int t = 0; t < 16; ++t) {
            const float4 a0 = sbuf[p][1][t][ty*2+0];
            const float4 a1 = sbuf[p][1][t][ty*2+1];
            const float4 bv = sbuf[p][0][t][tx];
            fma4(acc[0], a0.x, bv); fma4(acc[1], a0.y, bv);
            fma4(acc[2], a0.z, bv); fma4(acc[3], a0.w, bv);
            fma4(acc[4], a1.x, bv); fma4(acc[5], a1.y, bv);
            fma4(acc[6], a1.z, bv); fma4(acc[7], a1.w, bv);
        }
        // xw logit base: group (row,tensor), 16 lanes x 8 elems each
        {
            const float4 r0 = sbuf[p][xten][xrow][xl*2+0];
            const float4 r1 = sbuf[p][xten][xrow][xl*2+1];
            float d = dot4(r0, sW[xten][xl*2+0]) + dot4(r1, sW[xten][xl*2+1]);
            d += __shfl_xor(d, 1); d += __shfl_xor(d, 2);
            d += __shfl_xor(d, 4); d += __shfl_xor(d, 8);
            if (xl == 0) {
                int t = g*256 + k*16 + xrow;
                et_out[t] = d + bias[t];
            }
        }
        // psx column partials (thread owns one (tensor,col,half))
        {
            const float* sp = (const float*)&sbuf[p][p_ten][p_half*8][0];
            #pragma unroll
            for (int r = 0; r < 8; ++r) psx_acc += sp[r*E_ + p_col];
        }
        if (k < 15) {   // buf[1-p] last read at iter k-1, barrier'd -> safe
            sbuf[1-p][0][ty][tx] = n0;
            sbuf[1-p][1][ty][tx] = n1;
        }
        __syncthreads();
    }

    float4* pMW = (float4*)(ws + WS_PM) + ((size_t)(b*8 + g))*4096;
    #pragma unroll
    for (int i = 0; i < 8; ++i) pMW[(ty*8 + i)*32 + tx] = acc[i];

    const int pi = b*16 + g*2 + p_half;
    if (p_ten == 0) ws[WS_PSX1 + pi*E_ + p_col] = psx_acc;
    else            ws[WS_PSX2 + pi*E_ + p_col] = psx_acc;
}

// ---- KB: reduce psx -> sx; stream M partials ONCE computing both
//          c1[e] = (1/T) sum_f M[e,f] sx2[f]  (row dots, lane-reduced)
//          c2[f] = (1/T) sum_e sx1[e] M[e,f]  (coalesced col accumulation) ----
__global__ __launch_bounds__(256)
void kb_c(float* __restrict__ ws) {
    __shared__ float  sx1s[E_];
    __shared__ float4 sx2v[32];
    __shared__ float4 c2p[8][32];
    const int b = blockIdx.x, tid = threadIdx.x;
    if (tid < 128) {
        float s = 0.f;
        #pragma unroll
        for (int i = 0; i < 16; ++i) s += ws[WS_PSX2 + (b*16 + i)*E_ + tid];
        ((float*)sx2v)[tid] = s;
    } else {
        float s = 0.f;
        #pragma unroll
        for (int i = 0; i < 16; ++i) s += ws[WS_PSX1 + (b*16 + i)*E_ + (tid-128)];
        sx1s[tid-128] = s;
    }
    __syncthreads();
    const int hw = tid>>5, j = tid&31;          // 8 half-waves x 32 lanes
    const float4* pM4 = (const float4*)(ws + WS_PM) + ((size_t)b*8)*4096;
    const float4 sxj = sx2v[j];
    float4 c2a = {0.f,0.f,0.f,0.f};
    #pragma unroll
    for (int r = 0; r < 16; ++r) {
        const int e = hw*16 + r;
        const float s1 = sx1s[e];
        float ca = 0.f;
        #pragma unroll
        for (int gg = 0; gg < 8; ++gg) {
            float4 v = pM4[gg*4096 + e*32 + j];
            ca += dot4(v, sxj);
            fma4(c2a, s1, v);
        }
        #pragma unroll
        for (int m = 1; m <= 16; m <<= 1) ca += __shfl_xor(ca, m);
        if (j == 0) ws[WS_C1 + b*E_ + e] = ca * INV_T;
    }
    c2p[hw][j] = c2a;
    __syncthreads();
    if (tid < 128) {
        float s = 0.f;
        #pragma unroll
        for (int h = 0; h < 8; ++h) s += ((const float*)c2p[h])[tid];
        ws[WS_C2 + b*E_ + tid] = s * INV_T;
    }
}

// ---- KC: et += c.U, t-chunked (128 t / block), c for ALL batches in LDS.
//      U read exactly once total (2 MB), coalesced float4 rows. ----
__global__ __launch_bounds__(256)
void kc_etU(const float* __restrict__ U1, const float* __restrict__ U2,
            float* __restrict__ ws) {
    __shared__ float s_c[B_][E_];          // 16 KB
    const int ch = blockIdx.x, sel = blockIdx.y, tid = threadIdx.x;
    const float4* c4g = (const float4*)(ws + (sel ? WS_C2 : WS_C1));
    float4* s_c4 = (float4*)&s_c[0][0];
    #pragma unroll
    for (int i = 0; i < 4; ++i) s_c4[tid + 256*i] = c4g[tid + 256*i];
    __syncthreads();
    const float4* U4 = (const float4*)(sel ? U2 : U1);   // E x T/4
    const int c4i = tid&31, bg = tid>>5;                 // bg: 8 groups of 4 batches
    float4 acc[4];
    #pragma unroll
    for (int q = 0; q < 4; ++q) acc[q] = make_float4(0.f,0.f,0.f,0.f);
    #pragma unroll 4
    for (int e = 0; e < E_; ++e) {
        const float4 u = U4[(size_t)e*(T_/4) + ch*32 + c4i];
        fma4(acc[0], s_c[bg*4+0][e], u);
        fma4(acc[1], s_c[bg*4+1][e], u);
        fma4(acc[2], s_c[bg*4+2][e], u);
        fma4(acc[3], s_c[bg*4+3][e], u);
    }
    float4* et4 = (float4*)(ws + (sel ? WS_ET2 : WS_ET1));
    #pragma unroll
    for (int q = 0; q < 4; ++q) {
        const int bb = bg*4 + q;
        const size_t idx = (size_t)bb*(T_/4) + ch*32 + c4i;
        float4 v = et4[idx];          // xw base from KA
        add4(v, acc[q]);
        et4[idx] = v;
    }
}

// ---- KD: softmax over t -> probs in place; zero out for KE's atomics ----
__global__ __launch_bounds__(512)
void kd_softmax(float* __restrict__ ws, float* __restrict__ out) {
    __shared__ float red[512];
    const int b = blockIdx.x, sel = blockIdx.y, tid = threadIdx.x;
    float4* et4 = (float4*)(ws + (sel ? WS_ET2 : WS_ET1) + (size_t)b*T_);
    float4 v = et4[tid];
    if (tid < E_) out[b*2*E_ + sel*E_ + tid] = 0.f;
    float m = fmaxf(fmaxf(v.x, v.y), fmaxf(v.z, v.w));
    red[tid] = m; __syncthreads();
    for (int s = 256; s > 0; s >>= 1) {
        if (tid < s) red[tid] = fmaxf(red[tid], red[tid+s]);
        __syncthreads();
    }
    m = red[0]; __syncthreads();
    float4 e4;
    e4.x = __expf(v.x - m); e4.y = __expf(v.y - m);
    e4.z = __expf(v.z - m); e4.w = __expf(v.w - m);
    red[tid] = e4.x + e4.y + e4.z + e4.w;
    __syncthreads();
    for (int s = 256; s > 0; s >>= 1) {
        if (tid < s) red[tid] += red[tid+s];
        __syncthreads();
    }
    const float il = 1.f / red[0];
    e4.x *= il; e4.y *= il; e4.z *= il; e4.w *= il;
    et4[tid] = e4;
}

// ---- KE: o = sum_t at[t]*x[t,:] (proven K5, unchanged) ----
__global__ __launch_bounds__(256)
void ke_out(const float* __restrict__ x1, const float* __restrict__ x2,
            const float* __restrict__ ws, float* __restrict__ out) {
    __shared__ float4 s_r1[256], s_r2[256];
    __shared__ float s_p1[128], s_p2[128];
    const int b = blockIdx.x, g = blockIdx.y, tid = threadIdx.x;
    const float* pr1 = ws + WS_ET1 + (size_t)b*T_ + g*128;
    const float* pr2 = ws + WS_ET2 + (size_t)b*T_ + g*128;
    if (tid < 128) s_p1[tid] = pr1[tid];
    else           s_p2[tid - 128] = pr2[tid - 128];
    __syncthreads();
    const float4* p1 = (const float4*)x1 + ((size_t)b*T_ + g*128)*EV;
    const float4* p2 = (const float4*)x2 + ((size_t)b*T_ + g*128)*EV;
    const int rg = tid >> 5, q = tid & 31;
    float4 a1 = {0,0,0,0}, a2 = {0,0,0,0};
    #pragma unroll
    for (int i = 0; i < 16; ++i) {
        int r = i*8 + rg;
        fma4(a1, s_p1[r], p1[r*EV + q]);
        fma4(a2, s_p2[r], p2[r*EV + q]);
    }
    s_r1[tid] = a1; s_r2[tid] = a2;
    __syncthreads();
    for (int s = 128; s >= 32; s >>= 1) {
        if (tid < s) { add4(s_r1[tid], s_r1[tid+s]); add4(s_r2[tid], s_r2[tid+s]); }
        __syncthreads();
    }
    if (tid < 32) {
        float4 t1 = s_r1[tid], t2 = s_r2[tid];
        atomicAdd(&out[b*2*E_ + tid*4+0], t1.x);
        atomicAdd(&out[b*2*E_ + tid*4+1], t1.y);
        atomicAdd(&out[b*2*E_ + tid*4+2], t1.z);
        atomicAdd(&out[b*2*E_ + tid*4+3], t1.w);
        atomicAdd(&out[b*2*E_ + E_ + tid*4+0], t2.x);
        atomicAdd(&out[b*2*E_ + E_ + tid*4+1], t2.y);
        atomicAdd(&out[b*2*E_ + E_ + tid*4+2], t2.z);
        atomicAdd(&out[b*2*E_ + E_ + tid*4+3], t2.w);
    }
}

extern "C" void kernel_launch(void* const* d_in, const int* in_sizes, int n_in,
                              void* d_out, int out_size, void* d_ws, size_t ws_size,
                              hipStream_t stream) {
    const float* x1 = (const float*)d_in[0];
    const float* x2 = (const float*)d_in[1];
    const float* W1 = (const float*)d_in[2];
    const float* b1 = (const float*)d_in[3];
    const float* U1 = (const float*)d_in[4];
    const float* W2 = (const float*)d_in[5];
    const float* b2 = (const float*)d_in[6];
    const float* U2 = (const float*)d_in[7];
    float* ws  = (float*)d_ws;
    float* out = (float*)d_out;

    ka_gram<<<dim3(B_, 8), 512, 0, stream>>>(x1, x2, W1, b1, W2, b2, ws);
    kb_c<<<dim3(B_), 256, 0, stream>>>(ws);
    kc_etU<<<dim3(16, 2), 256, 0, stream>>>(U1, U2, ws);
    kd_softmax<<<dim3(B_, 2), 512, 0, stream>>>(ws, out);
    ke_out<<<dim3(B_, 16), 256, 0, stream>>>(x1, x2, ws, out);
}

// Round 3
// 188.730 us; speedup vs baseline: 1.0743x; 1.0743x over previous
//
#include <hip/hip_runtime.h>

// B=32, T=2048, E=128, fp32. Gram restructure, v2.1 (race fix):
//   KA: one pass over x per (b, 128-row chunk): M_g = X2c^T X1c (reg-tiled
//       8x8/thread, swizzled LDS), psx partials + x.W logit bases from the
//       prefetch registers.  512 blocks (2/CU).
//   KB: (B,2) blocks: c1 = M.sx2/T (rows) | c2 = M^T.sx1/T (cols).
//   KC: et += c.U chunked (U read once, 2MB).  KD: softmax.  KE: o-pass.
// R2 bug: prologue read sW before any barrier; sW written by tids 0-63 only
// -> waves 1-3 read uninit LDS -> et rows 0..7 (mod 128) garbage, absmax 5.9.
// Fix: __syncthreads() after sW store, before prologue xw dot.

#define B_ 32
#define T_ 2048
#define E_ 128
#define EV (E_/4)
#define INV_T (1.0f/2048.0f)
#define RC 128      // rows per KA block
#define BK 8        // k-step rows
#define NSTEP (RC/BK)
#define NG (T_/RC)  // 16 chunks

// ws float offsets (every slot written before read -> no zeroing needed)
#define WS_PSX1 0                      // B*NG*E = 65536
#define WS_PSX2 65536                  // B*NG*E
#define WS_PM   131072                 // B*NG*E*E = 8388608 (33.5MB)
#define WS_ET1  8519680                // B*T
#define WS_ET2  8585216                // B*T
#define WS_C1   8650752                // B*E
#define WS_C2   8654848                // B*E

__device__ __forceinline__ float dot4(float4 a, float4 b) {
    return a.x*b.x + a.y*b.y + a.z*b.z + a.w*b.w;
}
__device__ __forceinline__ void fma4(float4& a, float s, const float4 v) {
    a.x += s*v.x; a.y += s*v.y; a.z += s*v.z; a.w += s*v.w;
}
__device__ __forceinline__ void add4(float4& a, const float4 v) {
    a.x += v.x; a.y += v.y; a.z += v.z; a.w += v.w;
}

// ---- KA: Gram partial + psx partial + xw logit base, one x pass ----
__global__ __launch_bounds__(256)
void ka_gram(const float* __restrict__ x1, const float* __restrict__ x2,
             const float* __restrict__ W1, const float* __restrict__ b1,
             const float* __restrict__ W2, const float* __restrict__ b2,
             float* __restrict__ ws) {
    __shared__ float4 sbuf[2][2][BK][32];   // [dbuf][tensor][row][swz slot] 16KB
    __shared__ float4 sW[2][32];
    __shared__ float4 spx[512];             // psx epilogue scratch 8KB
    const int b = blockIdx.x, g = blockIdx.y, tid = threadIdx.x;
    if (tid < 64) sW[tid>>5][tid&31] = ((const float4*)((tid<32) ? W1 : W2))[tid&31];
    __syncthreads();   // sW visible to ALL waves before prologue xw dot (R2 fix)

    // staging role: tensor / row-in-chunk / col-pair
    const int ten = tid>>7, row = (tid>>4)&7, q = tid&15;
    // compute role: 8x8 tile at (e=ty*8.., f=tx*8..)
    const int ty = tid>>4, tx = tid&15;

    const float4* xg = (const float4*)(ten ? x2 : x1) + ((size_t)b*T_ + g*RC)*EV;
    const int loff = row*EV + 2*q;          // per-step load offset (float4)

    float* etp = ws + (ten ? WS_ET2 : WS_ET1) + (size_t)b*T_;
    const float* bias = ten ? b2 : b1;

    float4 acc[16];
    #pragma unroll
    for (int i = 0; i < 16; ++i) acc[i] = make_float4(0.f,0.f,0.f,0.f);
    float4 psa = {0,0,0,0}, psb = {0,0,0,0};

    // prologue: chunk 0 -> sbuf[0], plus its psx/xw
    {
        float4 n0 = xg[loff], n1 = xg[loff + 1];
        add4(psa, n0); add4(psb, n1);
        float d = dot4(n0, sW[ten][2*q]) + dot4(n1, sW[ten][2*q+1]);
        d += __shfl_xor(d, 1); d += __shfl_xor(d, 2);
        d += __shfl_xor(d, 4); d += __shfl_xor(d, 8);
        if (q == 0) { int t = g*RC + row; etp[t] = d + bias[t]; }
        sbuf[0][ten][row][q]      = n0;     // swz(2q)=q
        sbuf[0][ten][row][16 + q] = n1;     // swz(2q+1)=16+q
    }
    __syncthreads();

    for (int k = 0; k < NSTEP; ++k) {
        const int p = k & 1;
        float4 m0, m1;
        if (k < NSTEP-1) {
            m0 = xg[(k+1)*BK*EV + loff];
            m1 = xg[(k+1)*BK*EV + loff + 1];
        }
        #pragma unroll
        for (int t = 0; t < BK; ++t) {
            const float4 a0  = sbuf[p][1][t][ty];        // x2[e-block lo]
            const float4 a1  = sbuf[p][1][t][16 + ty];   // x2[e-block hi]
            const float4 bv0 = sbuf[p][0][t][tx];        // x1[f-block lo]
            const float4 bv1 = sbuf[p][0][t][16 + tx];   // x1[f-block hi]
            const float ae[8] = {a0.x,a0.y,a0.z,a0.w,a1.x,a1.y,a1.z,a1.w};
            #pragma unroll
            for (int i = 0; i < 8; ++i) {
                fma4(acc[2*i+0], ae[i], bv0);
                fma4(acc[2*i+1], ae[i], bv1);
            }
        }
        if (k < NSTEP-1) {
            add4(psa, m0); add4(psb, m1);
            float d = dot4(m0, sW[ten][2*q]) + dot4(m1, sW[ten][2*q+1]);
            d += __shfl_xor(d, 1); d += __shfl_xor(d, 2);
            d += __shfl_xor(d, 4); d += __shfl_xor(d, 8);
            if (q == 0) { int t = g*RC + (k+1)*BK + row; etp[t] = d + bias[t]; }
            sbuf[1-p][ten][row][q]      = m0;
            sbuf[1-p][ten][row][16 + q] = m1;
        }
        __syncthreads();
    }

    // M partial: logical layout [e][f4], e row stride 32 float4
    float4* pMW = (float4*)(ws + WS_PM) + (size_t)(b*NG + g)*4096;
    #pragma unroll
    for (int i = 0; i < 8; ++i) {
        pMW[(ty*8 + i)*32 + 2*tx + 0] = acc[2*i+0];
        pMW[(ty*8 + i)*32 + 2*tx + 1] = acc[2*i+1];
    }

    // psx partial: reduce over the 8 row-owners per (tensor, col-pair)
    spx[tid] = psa; spx[256 + tid] = psb;
    __syncthreads();
    if (tid < 64) {
        const int pt = tid>>5, c4p = tid&31;
        float4 s = {0,0,0,0};
        #pragma unroll
        for (int r = 0; r < 8; ++r)
            add4(s, spx[(c4p&1)*256 + pt*128 + r*16 + (c4p>>1)]);
        ((float4*)(ws + (pt ? WS_PSX2 : WS_PSX1)))[(size_t)(b*NG + g)*32 + c4p] = s;
    }
}

// ---- KB: sx reduce + c1 = M.sx2/T (sel 0) | c2 = M^T.sx1/T (sel 1) ----
__global__ __launch_bounds__(256)
void kb_c(float* __restrict__ ws) {
    __shared__ float  ssx[E_];
    __shared__ float4 c2p[8][32];
    const int b = blockIdx.x, sel = blockIdx.y, tid = threadIdx.x;
    if (tid < 128) {
        const float* ps = ws + (sel ? WS_PSX1 : WS_PSX2);  // c1 needs sx2, c2 needs sx1
        float s = 0.f;
        #pragma unroll
        for (int g = 0; g < NG; ++g) s += ps[(size_t)(b*NG + g)*E_ + tid];
        ssx[tid] = s;
    }
    __syncthreads();
    const float4* pM4 = (const float4*)(ws + WS_PM) + (size_t)b*NG*4096;
    if (sel == 0) {
        const int hw = tid>>5, j = tid&31;
        const float4 sxj = ((const float4*)ssx)[j];
        #pragma unroll
        for (int r = 0; r < 16; ++r) {
            const int e = hw*16 + r;
            float ca = 0.f;
            #pragma unroll
            for (int gg = 0; gg < NG; ++gg)
                ca += dot4(pM4[(size_t)gg*4096 + e*32 + j], sxj);
            #pragma unroll
            for (int m = 1; m <= 16; m <<= 1) ca += __shfl_xor(ca, m);
            if (j == 0) ws[WS_C1 + b*E_ + e] = ca * INV_T;
        }
    } else {
        const int h = tid>>5, j = tid&31;
        float4 a = {0,0,0,0};
        #pragma unroll
        for (int r = 0; r < 16; ++r) {
            const int e = h*16 + r;
            const float s1 = ssx[e];
            #pragma unroll
            for (int gg = 0; gg < NG; ++gg)
                fma4(a, s1, pM4[(size_t)gg*4096 + e*32 + j]);
        }
        c2p[h][j] = a;
        __syncthreads();
        if (tid < 128) {
            float s = 0.f;
            #pragma unroll
            for (int h2 = 0; h2 < 8; ++h2) s += ((const float*)c2p)[h2*128 + tid];
            ws[WS_C2 + b*E_ + tid] = s * INV_T;
        }
    }
}

// ---- KC: et += c.U, t-chunked (128 t / block), c for ALL batches in LDS ----
__global__ __launch_bounds__(256)
void kc_etU(const float* __restrict__ U1, const float* __restrict__ U2,
            float* __restrict__ ws) {
    __shared__ float s_c[B_][E_];          // 16 KB
    const int ch = blockIdx.x, sel = blockIdx.y, tid = threadIdx.x;
    const float4* c4g = (const float4*)(ws + (sel ? WS_C2 : WS_C1));
    float4* s_c4 = (float4*)&s_c[0][0];
    #pragma unroll
    for (int i = 0; i < 4; ++i) s_c4[tid + 256*i] = c4g[tid + 256*i];
    __syncthreads();
    const float4* U4 = (const float4*)(sel ? U2 : U1);   // E x T/4
    const int c4i = tid&31, bg = tid>>5;                 // 8 groups of 4 batches
    float4 acc[4];
    #pragma unroll
    for (int q = 0; q < 4; ++q) acc[q] = make_float4(0.f,0.f,0.f,0.f);
    #pragma unroll 4
    for (int e = 0; e < E_; ++e) {
        const float4 u = U4[(size_t)e*(T_/4) + ch*32 + c4i];
        fma4(acc[0], s_c[bg*4+0][e], u);
        fma4(acc[1], s_c[bg*4+1][e], u);
        fma4(acc[2], s_c[bg*4+2][e], u);
        fma4(acc[3], s_c[bg*4+3][e], u);
    }
    float4* et4 = (float4*)(ws + (sel ? WS_ET2 : WS_ET1));
    #pragma unroll
    for (int q = 0; q < 4; ++q) {
        const int bb = bg*4 + q;
        const size_t idx = (size_t)bb*(T_/4) + ch*32 + c4i;
        float4 v = et4[idx];          // xw base from KA
        add4(v, acc[q]);
        et4[idx] = v;
    }
}

// ---- KD: softmax over t -> probs in place; zero out for KE's atomics ----
__global__ __launch_bounds__(512)
void kd_softmax(float* __restrict__ ws, float* __restrict__ out) {
    __shared__ float red[512];
    const int b = blockIdx.x, sel = blockIdx.y, tid = threadIdx.x;
    float4* et4 = (float4*)(ws + (sel ? WS_ET2 : WS_ET1) + (size_t)b*T_);
    float4 v = et4[tid];
    if (tid < E_) out[b*2*E_ + sel*E_ + tid] = 0.f;
    float m = fmaxf(fmaxf(v.x, v.y), fmaxf(v.z, v.w));
    red[tid] = m; __syncthreads();
    for (int s = 256; s > 0; s >>= 1) {
        if (tid < s) red[tid] = fmaxf(red[tid], red[tid+s]);
        __syncthreads();
    }
    m = red[0]; __syncthreads();
    float4 e4;
    e4.x = __expf(v.x - m); e4.y = __expf(v.y - m);
    e4.z = __expf(v.z - m); e4.w = __expf(v.w - m);
    red[tid] = e4.x + e4.y + e4.z + e4.w;
    __syncthreads();
    for (int s = 256; s > 0; s >>= 1) {
        if (tid < s) red[tid] += red[tid+s];
        __syncthreads();
    }
    const float il = 1.f / red[0];
    e4.x *= il; e4.y *= il; e4.z *= il; e4.w *= il;
    et4[tid] = e4;
}

// ---- KE: o = sum_t at[t]*x[t,:] (proven) ----
__global__ __launch_bounds__(256)
void ke_out(const float* __restrict__ x1, const float* __restrict__ x2,
            const float* __restrict__ ws, float* __restrict__ out) {
    __shared__ float4 s_r1[256], s_r2[256];
    __shared__ float s_p1[128], s_p2[128];
    const int b = blockIdx.x, g = blockIdx.y, tid = threadIdx.x;
    const float* pr1 = ws + WS_ET1 + (size_t)b*T_ + g*128;
    const float* pr2 = ws + WS_ET2 + (size_t)b*T_ + g*128;
    if (tid < 128) s_p1[tid] = pr1[tid];
    else           s_p2[tid - 128] = pr2[tid - 128];
    __syncthreads();
    const float4* p1 = (const float4*)x1 + ((size_t)b*T_ + g*128)*EV;
    const float4* p2 = (const float4*)x2 + ((size_t)b*T_ + g*128)*EV;
    const int rg = tid >> 5, q = tid & 31;
    float4 a1 = {0,0,0,0}, a2 = {0,0,0,0};
    #pragma unroll
    for (int i = 0; i < 16; ++i) {
        int r = i*8 + rg;
        fma4(a1, s_p1[r], p1[r*EV + q]);
        fma4(a2, s_p2[r], p2[r*EV + q]);
    }
    s_r1[tid] = a1; s_r2[tid] = a2;
    __syncthreads();
    for (int s = 128; s >= 32; s >>= 1) {
        if (tid < s) { add4(s_r1[tid], s_r1[tid+s]); add4(s_r2[tid], s_r2[tid+s]); }
        __syncthreads();
    }
    if (tid < 32) {
        float4 t1 = s_r1[tid], t2 = s_r2[tid];
        atomicAdd(&out[b*2*E_ + tid*4+0], t1.x);
        atomicAdd(&out[b*2*E_ + tid*4+1], t1.y);
        atomicAdd(&out[b*2*E_ + tid*4+2], t1.z);
        atomicAdd(&out[b*2*E_ + tid*4+3], t1.w);
        atomicAdd(&out[b*2*E_ + E_ + tid*4+0], t2.x);
        atomicAdd(&out[b*2*E_ + E_ + tid*4+1], t2.y);
        atomicAdd(&out[b*2*E_ + E_ + tid*4+2], t2.z);
        atomicAdd(&out[b*2*E_ + E_ + tid*4+3], t2.w);
    }
}

extern "C" void kernel_launch(void* const* d_in, const int* in_sizes, int n_in,
                              void* d_out, int out_size, void* d_ws, size_t ws_size,
                              hipStream_t stream) {
    const float* x1 = (const float*)d_in[0];
    const float* x2 = (const float*)d_in[1];
    const float* W1 = (const float*)d_in[2];
    const float* b1 = (const float*)d_in[3];
    const float* U1 = (const float*)d_in[4];
    const float* W2 = (const float*)d_in[5];
    const float* b2 = (const float*)d_in[6];
    const float* U2 = (const float*)d_in[7];
    float* ws  = (float*)d_ws;
    float* out = (float*)d_out;

    ka_gram<<<dim3(B_, NG), 256, 0, stream>>>(x1, x2, W1, b1, W2, b2, ws);
    kb_c<<<dim3(B_, 2), 256, 0, stream>>>(ws);
    kc_etU<<<dim3(16, 2), 256, 0, stream>>>(U1, U2, ws);
    kd_softmax<<<dim3(B_, 2), 512, 0, stream>>>(ws, out);
    ke_out<<<dim3(B_, 16), 256, 0, stream>>>(x1, x2, ws, out);
}